// Round 4
// baseline (131.373 us; speedup 1.0000x reference)
//
#include <hip/hip_runtime.h>
#include <hip/hip_bf16.h>
#include <float.h>

// ---------------------------------------------------------------------------
// StageJointExpertRouter: h = relu(x@w1+b1); logits = h@w2+b2; top-k mask;
// softmax.  x [32768,1024] f32, w1 [1024,256], w2 [256,64].
// Outputs concat f32: logits [N,64], masked [N,64], probs [N,64].
//
// Both GEMMs use split-fp16 MFMA (xh*wh + xh*wl + xl*wh, f32 accum):
// logit deviation stays at f32-rounding level (~1e-6) -> top-k safe
// (passed twice with this error class).
// ---------------------------------------------------------------------------

#define N_ROWS 32768
#define D_IN   1024
#define D_H    256
#define N_E    64
#define NEG_INF_VAL (-1000000000.0f)

typedef _Float16 f16x8 __attribute__((ext_vector_type(8)));
typedef float    f32x4  __attribute__((ext_vector_type(4)));
typedef float    f32x16 __attribute__((ext_vector_type(16)));

// ========= Kernel 0: split w1 -> whT/wlT, w2 -> w2hT/w2lT (fp16, T) ========
__global__ __launch_bounds__(256) void split_weights_kernel(
    const float* __restrict__ w1, const float* __restrict__ w2,
    _Float16* __restrict__ whT, _Float16* __restrict__ wlT,
    _Float16* __restrict__ w2hT, _Float16* __restrict__ w2lT) {
  int idx = blockIdx.x * 256 + threadIdx.x;
  if (idx < D_IN * D_H) {
    const int k = idx >> 8;   // 0..1023
    const int n = idx & 255;
    const float v = w1[idx];
    const _Float16 hi = (_Float16)v;
    const _Float16 lo = (_Float16)(v - (float)hi);
    whT[n * D_IN + k] = hi;
    wlT[n * D_IN + k] = lo;
  } else {
    idx -= D_IN * D_H;        // 0..16383
    const int k = idx >> 6;   // 0..255
    const int e = idx & 63;
    const float v = w2[idx];
    const _Float16 hi = (_Float16)v;
    const _Float16 lo = (_Float16)(v - (float)hi);
    w2hT[e * D_H + k] = hi;
    w2lT[e * D_H + k] = lo;
  }
}

// ============== Kernel 1: h = relu(x@w1+b1) via split-fp16 MFMA ============
// Block: 256 thr (4 waves), tile 64 rows x 256 cols (ALL of N -> x read once).
// Wave w owns cols [w*64, w*64+64) as 2x2 frags of 32x32.
// A (x) split to hi/lo fp16, double-buffered in LDS: BK=64, row = 256 bytes
// [hi 128B | lo 128B], swizzle kbyte ^= (row&7)<<4 (2-way/phase = free).
// B (w1 pre-split fp16) loaded global->reg per kf: L2-hot, no barriers.
// One barrier per K-iter; next iter's x loads issued before the MFMA phase.
__global__ __launch_bounds__(256) void gemm1_mfma_kernel(
    const float* __restrict__ x, const _Float16* __restrict__ whT,
    const _Float16* __restrict__ wlT, const float* __restrict__ b1,
    float* __restrict__ h) {
  __shared__ char lds[32768];  // 2 bufs x (64 rows x 256B)

  const int t  = threadIdx.x;
  const int m0 = blockIdx.x * 64;

  // staging coords: thread -> (row, 16-elem k-slice)
  const int srow = t >> 2;            // 0..63
  const int skb2 = (t & 3) * 32;      // byte offset of 16-elem slice (hi half)
  const int sw   = (srow & 7) << 4;

  // fragment coords
  const int wv   = t >> 6;            // wave 0..3 -> col base wv*64
  const int lane = t & 63;
  const int l31  = lane & 31;
  const int kg   = lane >> 5;         // k-group 0..1 (8 elems each)

  const float* xrowp = x + (size_t)(m0 + srow) * D_IN + (t & 3) * 16;

  f32x16 acc[2][2];
#pragma unroll
  for (int i = 0; i < 16; ++i) {
    acc[0][0][i] = 0.f; acc[0][1][i] = 0.f;
    acc[1][0][i] = 0.f; acc[1][1][i] = 0.f;
  }

#define STAGE_WRITE(bufi, q0, q1, q2, q3)                                    \
  do {                                                                       \
    const float vv[16] = {q0.x, q0.y, q0.z, q0.w, q1.x, q1.y, q1.z, q1.w,    \
                          q2.x, q2.y, q2.z, q2.w, q3.x, q3.y, q3.z, q3.w};   \
    f16x8 hi0, hi1, lo0, lo1;                                                \
    _Pragma("unroll") for (int j = 0; j < 8; ++j) {                          \
      const _Float16 hv = (_Float16)vv[j];                                   \
      hi0[j] = hv; lo0[j] = (_Float16)(vv[j] - (float)hv);                   \
    }                                                                        \
    _Pragma("unroll") for (int j = 0; j < 8; ++j) {                          \
      const _Float16 hv = (_Float16)vv[8 + j];                               \
      hi1[j] = hv; lo1[j] = (_Float16)(vv[8 + j] - (float)hv);               \
    }                                                                        \
    char* bb = lds + (bufi) * 16384 + srow * 256;                            \
    *(f16x8*)(bb + ((skb2 + 0) ^ sw)) = hi0;                                 \
    *(f16x8*)(bb + ((skb2 + 16) ^ sw)) = hi1;                                \
    *(f16x8*)(bb + 128 + ((skb2 + 0) ^ sw)) = lo0;                           \
    *(f16x8*)(bb + 128 + ((skb2 + 16) ^ sw)) = lo1;                          \
  } while (0)

  // ---- prologue: stage iter 0 ----
  {
    const float4* xp = (const float4*)(xrowp);
    const float4 q0 = xp[0], q1 = xp[1], q2 = xp[2], q3 = xp[3];
    STAGE_WRITE(0, q0, q1, q2, q3);
  }
  __syncthreads();

  const _Float16* bhp0 = whT + (size_t)(wv * 64 + l31) * D_IN + kg * 8;
  const _Float16* blp0 = wlT + (size_t)(wv * 64 + l31) * D_IN + kg * 8;

  for (int it = 0; it < 16; ++it) {
    // ---- issue next iter's x loads (hide under MFMA phase) ----
    float4 p0, p1, p2, p3;
    if (it + 1 < 16) {
      const float4* xp = (const float4*)(xrowp + (it + 1) * 64);
      p0 = xp[0]; p1 = xp[1]; p2 = xp[2]; p3 = xp[3];
    }

    const char* rb = lds + (it & 1) * 16384;
    const _Float16* bhp = bhp0 + it * 64;
    const _Float16* blp = blp0 + it * 64;

#pragma unroll
    for (int kf = 0; kf < 4; ++kf) {
      const f16x8 bh0 = *(const f16x8*)(bhp + kf * 16);
      const f16x8 bl0 = *(const f16x8*)(blp + kf * 16);
      const f16x8 bh1 = *(const f16x8*)(bhp + 32 * D_IN + kf * 16);
      const f16x8 bl1 = *(const f16x8*)(blp + 32 * D_IN + kf * 16);
      const int kb = kf * 32 + kg * 16;
#pragma unroll
      for (int mf = 0; mf < 2; ++mf) {
        const int ra = mf * 32 + l31;
        const char* ap = rb + ra * 256 + (kb ^ ((ra & 7) << 4));
        const f16x8 ah = *(const f16x8*)(ap);
        const f16x8 al = *(const f16x8*)(ap + 128);
        acc[mf][0] = __builtin_amdgcn_mfma_f32_32x32x16_f16(al, bh0, acc[mf][0], 0, 0, 0);
        acc[mf][0] = __builtin_amdgcn_mfma_f32_32x32x16_f16(ah, bl0, acc[mf][0], 0, 0, 0);
        acc[mf][0] = __builtin_amdgcn_mfma_f32_32x32x16_f16(ah, bh0, acc[mf][0], 0, 0, 0);
        acc[mf][1] = __builtin_amdgcn_mfma_f32_32x32x16_f16(al, bh1, acc[mf][1], 0, 0, 0);
        acc[mf][1] = __builtin_amdgcn_mfma_f32_32x32x16_f16(ah, bl1, acc[mf][1], 0, 0, 0);
        acc[mf][1] = __builtin_amdgcn_mfma_f32_32x32x16_f16(ah, bh1, acc[mf][1], 0, 0, 0);
      }
    }

    if (it + 1 < 16) {
      STAGE_WRITE((it + 1) & 1, p0, p1, p2, p3);
    }
    __syncthreads();
  }

  // ---- epilogue: + b1, ReLU, store ----
  // C/D 32x32 layout: col = lane&31, row = (r&3) + 8*(r>>2) + 4*(lane>>5)
#pragma unroll
  for (int nf = 0; nf < 2; ++nf) {
    const int colg = wv * 64 + nf * 32 + l31;
    const float bias = b1[colg];
#pragma unroll
    for (int mf = 0; mf < 2; ++mf) {
#pragma unroll
      for (int r = 0; r < 16; ++r) {
        const int row = (r & 3) + 8 * (r >> 2) + 4 * kg;
        const int mg = m0 + mf * 32 + row;
        h[(size_t)mg * D_H + colg] = fmaxf(acc[mf][nf][r] + bias, 0.0f);
      }
    }
  }
#undef STAGE_WRITE
}

// ======= Kernel 2: router via MFMA, zero LDS, no barriers in k-loop ========
// 256 thr = 4 waves; wave tile = 16 rows x 64 experts (4 C-frags 16x16).
// C layout (16x16x32): col = lane&15, row = (lane>>4)*4 + reg.
__global__ __launch_bounds__(256) void router_mfma_kernel(
    const float* __restrict__ h, const _Float16* __restrict__ w2hT,
    const _Float16* __restrict__ w2lT, const float* __restrict__ b2,
    const int* __restrict__ topk_p, float* __restrict__ out_logits,
    float* __restrict__ out_masked, float* __restrict__ out_probs) {
  const int t    = threadIdx.x;
  const int wid  = t >> 6;
  const int lane = t & 63;
  const int c    = lane & 15;   // A-row / B-col selector
  const int kg   = lane >> 4;   // k-group 0..3 (also C row-group)

  const int rowbase = blockIdx.x * 64 + wid * 16;

  f32x4 acc0 = {0.f, 0.f, 0.f, 0.f};
  f32x4 acc1 = {0.f, 0.f, 0.f, 0.f};
  f32x4 acc2 = {0.f, 0.f, 0.f, 0.f};
  f32x4 acc3 = {0.f, 0.f, 0.f, 0.f};

  const float*    hp  = h    + (size_t)(rowbase + c) * D_H + kg * 8;
  const _Float16* bhp = w2hT + c * D_H + kg * 8;
  const _Float16* blp = w2lT + c * D_H + kg * 8;

#pragma unroll
  for (int s = 0; s < 8; ++s) {            // K = 256 = 8 slices of 32
    const float4 a0 = *(const float4*)(hp + s * 32);
    const float4 a1 = *(const float4*)(hp + s * 32 + 4);
    const float av[8] = {a0.x, a0.y, a0.z, a0.w, a1.x, a1.y, a1.z, a1.w};
    f16x8 ah, al;
#pragma unroll
    for (int j = 0; j < 8; ++j) {
      const _Float16 hv = (_Float16)av[j];
      ah[j] = hv;
      al[j] = (_Float16)(av[j] - (float)hv);
    }
    const f16x8 bh0 = *(const f16x8*)(bhp + 0 * 16 * D_H + s * 32);
    const f16x8 bl0 = *(const f16x8*)(blp + 0 * 16 * D_H + s * 32);
    const f16x8 bh1 = *(const f16x8*)(bhp + 1 * 16 * D_H + s * 32);
    const f16x8 bl1 = *(const f16x8*)(blp + 1 * 16 * D_H + s * 32);
    const f16x8 bh2 = *(const f16x8*)(bhp + 2 * 16 * D_H + s * 32);
    const f16x8 bl2 = *(const f16x8*)(blp + 2 * 16 * D_H + s * 32);
    const f16x8 bh3 = *(const f16x8*)(bhp + 3 * 16 * D_H + s * 32);
    const f16x8 bl3 = *(const f16x8*)(blp + 3 * 16 * D_H + s * 32);
    acc0 = __builtin_amdgcn_mfma_f32_16x16x32_f16(al, bh0, acc0, 0, 0, 0);
    acc0 = __builtin_amdgcn_mfma_f32_16x16x32_f16(ah, bl0, acc0, 0, 0, 0);
    acc0 = __builtin_amdgcn_mfma_f32_16x16x32_f16(ah, bh0, acc0, 0, 0, 0);
    acc1 = __builtin_amdgcn_mfma_f32_16x16x32_f16(al, bh1, acc1, 0, 0, 0);
    acc1 = __builtin_amdgcn_mfma_f32_16x16x32_f16(ah, bl1, acc1, 0, 0, 0);
    acc1 = __builtin_amdgcn_mfma_f32_16x16x32_f16(ah, bh1, acc1, 0, 0, 0);
    acc2 = __builtin_amdgcn_mfma_f32_16x16x32_f16(al, bh2, acc2, 0, 0, 0);
    acc2 = __builtin_amdgcn_mfma_f32_16x16x32_f16(ah, bl2, acc2, 0, 0, 0);
    acc2 = __builtin_amdgcn_mfma_f32_16x16x32_f16(ah, bh2, acc2, 0, 0, 0);
    acc3 = __builtin_amdgcn_mfma_f32_16x16x32_f16(al, bh3, acc3, 0, 0, 0);
    acc3 = __builtin_amdgcn_mfma_f32_16x16x32_f16(ah, bl3, acc3, 0, 0, 0);
    acc3 = __builtin_amdgcn_mfma_f32_16x16x32_f16(ah, bh3, acc3, 0, 0, 0);
  }

  const int K = topk_p[0];
  const bool doMask = (K > 0 && K < N_E);
  const float b2v0 = b2[c], b2v1 = b2[16 + c], b2v2 = b2[32 + c],
              b2v3 = b2[48 + c];

#pragma unroll
  for (int r = 0; r < 4; ++r) {
    const int row = rowbase + kg * 4 + r;
    float* lg = out_logits + (size_t)row * N_E;
    float* mk = out_masked + (size_t)row * N_E;
    float* pb = out_probs  + (size_t)row * N_E;

    const float v0 = acc0[r] + b2v0;
    const float v1 = acc1[r] + b2v1;
    const float v2 = acc2[r] + b2v2;
    const float v3 = acc3[r] + b2v3;
    lg[c] = v0; lg[16 + c] = v1; lg[32 + c] = v2; lg[48 + c] = v3;

    // ---- top-k (argmax K times over 16 lanes x 4 frags, min-idx ties) ----
    bool s0 = true, s1 = true, s2 = true, s3 = true;
    if (doMask) {
      s0 = s1 = s2 = s3 = false;
      float c0 = v0, c1 = v1, c2 = v2, c3 = v3;
      for (int it = 0; it < K; ++it) {
        float m = c0; int mi = c;
        if (c1 > m) { m = c1; mi = 16 + c; }
        if (c2 > m) { m = c2; mi = 32 + c; }
        if (c3 > m) { m = c3; mi = 48 + c; }
#pragma unroll
        for (int off = 1; off <= 8; off <<= 1) {
          const float om = __shfl_xor(m, off);
          const int   oi = __shfl_xor(mi, off);
          if (om > m || (om == m && oi < mi)) { m = om; mi = oi; }
        }
        if ((mi & 15) == c) {
          const int f = mi >> 4;
          s0 = s0 || (f == 0); c0 = (f == 0) ? -FLT_MAX : c0;
          s1 = s1 || (f == 1); c1 = (f == 1) ? -FLT_MAX : c1;
          s2 = s2 || (f == 2); c2 = (f == 2) ? -FLT_MAX : c2;
          s3 = s3 || (f == 3); c3 = (f == 3) ? -FLT_MAX : c3;
        }
      }
    }
    const float m0 = s0 ? v0 : NEG_INF_VAL;
    const float m1 = s1 ? v1 : NEG_INF_VAL;
    const float m2 = s2 ? v2 : NEG_INF_VAL;
    const float m3 = s3 ? v3 : NEG_INF_VAL;
    mk[c] = m0; mk[16 + c] = m1; mk[32 + c] = m2; mk[48 + c] = m3;

    // ---- softmax over masked ----
    float mx = fmaxf(fmaxf(m0, m1), fmaxf(m2, m3));
#pragma unroll
    for (int off = 1; off <= 8; off <<= 1) mx = fmaxf(mx, __shfl_xor(mx, off));
    const float e0 = __expf(m0 - mx);
    const float e1 = __expf(m1 - mx);
    const float e2 = __expf(m2 - mx);
    const float e3 = __expf(m3 - mx);
    float sm = e0 + e1 + e2 + e3;
#pragma unroll
    for (int off = 1; off <= 8; off <<= 1) sm += __shfl_xor(sm, off);
    const float inv = 1.0f / sm;
    pb[c] = e0 * inv; pb[16 + c] = e1 * inv; pb[32 + c] = e2 * inv;
    pb[48 + c] = e3 * inv;
  }
}

// ============================== launcher ===================================
extern "C" void kernel_launch(void* const* d_in, const int* in_sizes, int n_in,
                              void* d_out, int out_size, void* d_ws,
                              size_t ws_size, hipStream_t stream) {
  const float* x  = (const float*)d_in[0];
  const float* w1 = (const float*)d_in[1];
  const float* b1 = (const float*)d_in[2];
  const float* w2 = (const float*)d_in[3];
  const float* b2 = (const float*)d_in[4];
  const int* topk = (const int*)d_in[5];

  char* ws = (char*)d_ws;
  _Float16* whT  = (_Float16*)(ws);                  // 512 KB
  _Float16* wlT  = (_Float16*)(ws + 524288);         // 512 KB
  _Float16* w2hT = (_Float16*)(ws + 1048576);        // 32 KB
  _Float16* w2lT = (_Float16*)(ws + 1081344);        // 32 KB
  float*    hbuf = (float*)(ws + 1114112);           // 33.5 MB

  float* out_logits = (float*)d_out;
  float* out_masked = out_logits + (size_t)N_ROWS * N_E;
  float* out_probs  = out_masked + (size_t)N_ROWS * N_E;

  split_weights_kernel<<<(D_IN * D_H + D_H * N_E) / 256, 256, 0, stream>>>(
      w1, w2, whT, wlT, w2hT, w2lT);

  gemm1_mfma_kernel<<<N_ROWS / 64, 256, 0, stream>>>(x, whT, wlT, b1, hbuf);

  router_mfma_kernel<<<N_ROWS / 64, 256, 0, stream>>>(
      hbuf, w2hT, w2lT, b2, topk, out_logits, out_masked, out_probs);
}

// Round 5
// 102.356 us; speedup vs baseline: 1.2835x; 1.2835x over previous
//
#include <hip/hip_runtime.h>
#include <hip/hip_bf16.h>
#include <float.h>

// ---------------------------------------------------------------------------
// StageJointExpertRouter: h = relu(x@w1+b1); logits = h@w2+b2; top-k mask;
// softmax.  x [32768,1024] f32, w1 [1024,256], w2 [256,64].
// Outputs concat f32: logits [N,64], masked [N,64], probs [N,64].
//
// Both GEMMs use split-fp16 MFMA (xh*wh + xh*wl + xl*wh, f32 accum):
// logit deviation stays at f32-rounding level (~1e-6) -> top-k safe
// (passed 3x with this error class).
// ---------------------------------------------------------------------------

#define N_ROWS 32768
#define D_IN   1024
#define D_H    256
#define N_E    64
#define NEG_INF_VAL (-1000000000.0f)

typedef _Float16 f16x8 __attribute__((ext_vector_type(8)));
typedef float    f32x4  __attribute__((ext_vector_type(4)));
typedef float    f32x16 __attribute__((ext_vector_type(16)));

// ========= Kernel 0: split weights ========================================
// w1 -> fragment-packed fp16 hi/lo:
//   chunk(wv,it,kf,nf,lane) = (((wv*16+it)*4+kf)*2+nf)*64+lane, 8 elems/chunk
//   col n = wv*64+nf*32+(lane&31), k = it*64+kf*16+(lane>>5)*8+j
// w2 -> w2hT/w2lT [e][k] fp16 (transposed), as before.
__global__ __launch_bounds__(256) void split_weights_kernel(
    const float* __restrict__ w1, const float* __restrict__ w2,
    _Float16* __restrict__ w1pk_h, _Float16* __restrict__ w1pk_l,
    _Float16* __restrict__ w2hT, _Float16* __restrict__ w2lT) {
  int idx = blockIdx.x * 256 + threadIdx.x;
  if (idx < D_IN * D_H) {
    const int k = idx >> 8;   // 0..1023
    const int n = idx & 255;
    const float v = w1[idx];
    const _Float16 hi = (_Float16)v;
    const _Float16 lo = (_Float16)(v - (float)hi);
    const int wv = n >> 6, nf = (n >> 5) & 1, l31 = n & 31;
    const int it = k >> 6, kf = (k >> 4) & 3, kg = (k >> 3) & 1, j = k & 7;
    const int lane = kg * 32 + l31;
    const int off = ((((wv * 16 + it) * 4 + kf) * 2 + nf) * 64 + lane) * 8 + j;
    w1pk_h[off] = hi;
    w1pk_l[off] = lo;
  } else {
    idx -= D_IN * D_H;        // 0..16383
    const int k = idx >> 6;   // 0..255
    const int e = idx & 63;
    const float v = w2[idx];
    const _Float16 hi = (_Float16)v;
    const _Float16 lo = (_Float16)(v - (float)hi);
    w2hT[e * D_H + k] = hi;
    w2lT[e * D_H + k] = lo;
  }
}

// ============== Kernel 1: h = relu(x@w1+b1) via split-fp16 MFMA ============
// 512 blocks x 256 thr (4 waves); tile 64 rows x 256 cols (x read once).
// Wave wv owns cols [wv*64, wv*64+64) as 2x2 frags of 32x32.
// A (x): split hi/lo fp16, LDS double-buffered (BK=64, 256B rows, XOR swz).
// B (w1): fragment-packed fp16, global->reg, double-buffered (uh/ul, vh/vl).
// One barrier per K-iter; next iter's A+B loads issued before the MFMA phase.
__global__ __launch_bounds__(256, 2) void gemm1_mfma_kernel(
    const float* __restrict__ x, const _Float16* __restrict__ w1pk_h,
    const _Float16* __restrict__ w1pk_l, const float* __restrict__ b1,
    float* __restrict__ h) {
  __shared__ char lds[32768];  // 2 bufs x (64 rows x 256B)

  const int t  = threadIdx.x;
  const int m0 = blockIdx.x * 64;

  // staging coords
  const int srow = t >> 2;            // 0..63
  const int skb2 = (t & 3) * 32;      // byte offset of 16-elem slice
  const int sw   = (srow & 7) << 4;

  // fragment coords
  const int wv   = t >> 6;            // wave 0..3 -> col base wv*64
  const int lane = t & 63;
  const int l31  = lane & 31;
  const int kg   = lane >> 5;

  const float* xrowp = x + (size_t)(m0 + srow) * D_IN + (t & 3) * 16;
  const f16x8* bph = (const f16x8*)w1pk_h;
  const f16x8* bpl = (const f16x8*)w1pk_l;

  f32x16 acc[2][2];
#pragma unroll
  for (int i = 0; i < 16; ++i) {
    acc[0][0][i] = 0.f; acc[0][1][i] = 0.f;
    acc[1][0][i] = 0.f; acc[1][1][i] = 0.f;
  }

  f16x8 uh00, uh01, uh10, uh11, uh20, uh21, uh30, uh31;
  f16x8 ul00, ul01, ul10, ul11, ul20, ul21, ul30, ul31;
  f16x8 vh00, vh01, vh10, vh11, vh20, vh21, vh30, vh31;
  f16x8 vl00, vl01, vl10, vl11, vl20, vl21, vl30, vl31;

#define STAGE_WRITE(bufi, q0, q1, q2, q3)                                    \
  do {                                                                       \
    const float vv[16] = {q0.x, q0.y, q0.z, q0.w, q1.x, q1.y, q1.z, q1.w,    \
                          q2.x, q2.y, q2.z, q2.w, q3.x, q3.y, q3.z, q3.w};   \
    f16x8 hi0, hi1, lo0, lo1;                                                \
    _Pragma("unroll") for (int j = 0; j < 8; ++j) {                          \
      const _Float16 hv = (_Float16)vv[j];                                   \
      hi0[j] = hv; lo0[j] = (_Float16)(vv[j] - (float)hv);                   \
    }                                                                        \
    _Pragma("unroll") for (int j = 0; j < 8; ++j) {                          \
      const _Float16 hv = (_Float16)vv[8 + j];                               \
      hi1[j] = hv; lo1[j] = (_Float16)(vv[8 + j] - (float)hv);               \
    }                                                                        \
    char* bb = lds + (bufi) * 16384 + srow * 256;                            \
    *(f16x8*)(bb + ((skb2 + 0) ^ sw)) = hi0;                                 \
    *(f16x8*)(bb + ((skb2 + 16) ^ sw)) = hi1;                                \
    *(f16x8*)(bb + 128 + ((skb2 + 0) ^ sw)) = lo0;                           \
    *(f16x8*)(bb + 128 + ((skb2 + 16) ^ sw)) = lo1;                          \
  } while (0)

#define LOAD_B(BH, BL, itv)                                                  \
  do {                                                                       \
    const int ch = (wv * 16 + (itv)) * 512 + lane;                           \
    BH##00 = bph[ch + 0 * 64]; BH##01 = bph[ch + 1 * 64];                    \
    BH##10 = bph[ch + 2 * 64]; BH##11 = bph[ch + 3 * 64];                    \
    BH##20 = bph[ch + 4 * 64]; BH##21 = bph[ch + 5 * 64];                    \
    BH##30 = bph[ch + 6 * 64]; BH##31 = bph[ch + 7 * 64];                    \
    BL##00 = bpl[ch + 0 * 64]; BL##01 = bpl[ch + 1 * 64];                    \
    BL##10 = bpl[ch + 2 * 64]; BL##11 = bpl[ch + 3 * 64];                    \
    BL##20 = bpl[ch + 4 * 64]; BL##21 = bpl[ch + 5 * 64];                    \
    BL##30 = bpl[ch + 6 * 64]; BL##31 = bpl[ch + 7 * 64];                    \
  } while (0)

#define MFMA_KF(rb, kfv, BH0, BL0, BH1, BL1)                                 \
  do {                                                                       \
    const int kb = (kfv) * 32 + kg * 16;                                     \
    _Pragma("unroll") for (int mf = 0; mf < 2; ++mf) {                       \
      const int ra = mf * 32 + l31;                                          \
      const char* ap = (rb) + ra * 256 + (kb ^ ((ra & 7) << 4));             \
      const f16x8 ah = *(const f16x8*)(ap);                                  \
      const f16x8 al = *(const f16x8*)(ap + 128);                            \
      acc[mf][0] = __builtin_amdgcn_mfma_f32_32x32x16_f16(al, BH0, acc[mf][0], 0, 0, 0); \
      acc[mf][0] = __builtin_amdgcn_mfma_f32_32x32x16_f16(ah, BL0, acc[mf][0], 0, 0, 0); \
      acc[mf][0] = __builtin_amdgcn_mfma_f32_32x32x16_f16(ah, BH0, acc[mf][0], 0, 0, 0); \
      acc[mf][1] = __builtin_amdgcn_mfma_f32_32x32x16_f16(al, BH1, acc[mf][1], 0, 0, 0); \
      acc[mf][1] = __builtin_amdgcn_mfma_f32_32x32x16_f16(ah, BL1, acc[mf][1], 0, 0, 0); \
      acc[mf][1] = __builtin_amdgcn_mfma_f32_32x32x16_f16(ah, BH1, acc[mf][1], 0, 0, 0); \
    }                                                                        \
  } while (0)

#define GSTEP(ITV, LB, CH, CL, NH, NL)                                       \
  do {                                                                       \
    float4 p0, p1, p2, p3;                                                   \
    const bool more = (ITV) + 1 < 16;                                        \
    if (more) {                                                              \
      const float4* xp = (const float4*)(xrowp + ((ITV) + 1) * 64);          \
      p0 = xp[0]; p1 = xp[1]; p2 = xp[2]; p3 = xp[3];                        \
      LOAD_B(NH, NL, (ITV) + 1);                                             \
    }                                                                        \
    const char* rb = lds + (LB) * 16384;                                     \
    MFMA_KF(rb, 0, CH##00, CL##00, CH##01, CL##01);                          \
    MFMA_KF(rb, 1, CH##10, CL##10, CH##11, CL##11);                          \
    MFMA_KF(rb, 2, CH##20, CL##20, CH##21, CL##21);                          \
    MFMA_KF(rb, 3, CH##30, CL##30, CH##31, CL##31);                          \
    if (more) STAGE_WRITE(1 - (LB), p0, p1, p2, p3);                         \
    __syncthreads();                                                         \
  } while (0)

  // ---- prologue: stage A(0), load B(0) ----
  {
    const float4* xp = (const float4*)(xrowp);
    const float4 q0 = xp[0], q1 = xp[1], q2 = xp[2], q3 = xp[3];
    STAGE_WRITE(0, q0, q1, q2, q3);
    LOAD_B(uh, ul, 0);
  }
  __syncthreads();

  for (int ii = 0; ii < 8; ++ii) {
    GSTEP(2 * ii,     0, uh, ul, vh, vl);
    GSTEP(2 * ii + 1, 1, vh, vl, uh, ul);
  }

  // ---- epilogue: + b1, ReLU, store ----
  // C/D 32x32 layout: col = lane&31, row = (r&3) + 8*(r>>2) + 4*(lane>>5)
#pragma unroll
  for (int nf = 0; nf < 2; ++nf) {
    const int colg = wv * 64 + nf * 32 + l31;
    const float bias = b1[colg];
#pragma unroll
    for (int mf = 0; mf < 2; ++mf) {
#pragma unroll
      for (int r = 0; r < 16; ++r) {
        const int row = (r & 3) + 8 * (r >> 2) + 4 * kg;
        const int mg = m0 + mf * 32 + row;
        h[(size_t)mg * D_H + colg] = fmaxf(acc[mf][nf][r] + bias, 0.0f);
      }
    }
  }
#undef GSTEP
#undef MFMA_KF
#undef LOAD_B
#undef STAGE_WRITE
}

// ======= Kernel 2: router via MFMA, zero LDS, no barriers in k-loop ========
// 256 thr = 4 waves; wave tile = 16 rows x 64 experts (4 C-frags 16x16).
// C layout (16x16x32): col = lane&15, row = (lane>>4)*4 + reg.
__global__ __launch_bounds__(256) void router_mfma_kernel(
    const float* __restrict__ h, const _Float16* __restrict__ w2hT,
    const _Float16* __restrict__ w2lT, const float* __restrict__ b2,
    const int* __restrict__ topk_p, float* __restrict__ out_logits,
    float* __restrict__ out_masked, float* __restrict__ out_probs) {
  const int t    = threadIdx.x;
  const int wid  = t >> 6;
  const int lane = t & 63;
  const int c    = lane & 15;   // A-row / B-col selector
  const int kg   = lane >> 4;   // k-group 0..3 (also C row-group)

  const int rowbase = blockIdx.x * 64 + wid * 16;

  f32x4 acc0 = {0.f, 0.f, 0.f, 0.f};
  f32x4 acc1 = {0.f, 0.f, 0.f, 0.f};
  f32x4 acc2 = {0.f, 0.f, 0.f, 0.f};
  f32x4 acc3 = {0.f, 0.f, 0.f, 0.f};

  const float*    hp  = h    + (size_t)(rowbase + c) * D_H + kg * 8;
  const _Float16* bhp = w2hT + c * D_H + kg * 8;
  const _Float16* blp = w2lT + c * D_H + kg * 8;

#pragma unroll
  for (int s = 0; s < 8; ++s) {            // K = 256 = 8 slices of 32
    const float4 a0 = *(const float4*)(hp + s * 32);
    const float4 a1 = *(const float4*)(hp + s * 32 + 4);
    const float av[8] = {a0.x, a0.y, a0.z, a0.w, a1.x, a1.y, a1.z, a1.w};
    f16x8 ah, al;
#pragma unroll
    for (int j = 0; j < 8; ++j) {
      const _Float16 hv = (_Float16)av[j];
      ah[j] = hv;
      al[j] = (_Float16)(av[j] - (float)hv);
    }
    const f16x8 bh0 = *(const f16x8*)(bhp + 0 * 16 * D_H + s * 32);
    const f16x8 bl0 = *(const f16x8*)(blp + 0 * 16 * D_H + s * 32);
    const f16x8 bh1 = *(const f16x8*)(bhp + 1 * 16 * D_H + s * 32);
    const f16x8 bl1 = *(const f16x8*)(blp + 1 * 16 * D_H + s * 32);
    const f16x8 bh2 = *(const f16x8*)(bhp + 2 * 16 * D_H + s * 32);
    const f16x8 bl2 = *(const f16x8*)(blp + 2 * 16 * D_H + s * 32);
    const f16x8 bh3 = *(const f16x8*)(bhp + 3 * 16 * D_H + s * 32);
    const f16x8 bl3 = *(const f16x8*)(blp + 3 * 16 * D_H + s * 32);
    acc0 = __builtin_amdgcn_mfma_f32_16x16x32_f16(al, bh0, acc0, 0, 0, 0);
    acc0 = __builtin_amdgcn_mfma_f32_16x16x32_f16(ah, bl0, acc0, 0, 0, 0);
    acc0 = __builtin_amdgcn_mfma_f32_16x16x32_f16(ah, bh0, acc0, 0, 0, 0);
    acc1 = __builtin_amdgcn_mfma_f32_16x16x32_f16(al, bh1, acc1, 0, 0, 0);
    acc1 = __builtin_amdgcn_mfma_f32_16x16x32_f16(ah, bl1, acc1, 0, 0, 0);
    acc1 = __builtin_amdgcn_mfma_f32_16x16x32_f16(ah, bh1, acc1, 0, 0, 0);
    acc2 = __builtin_amdgcn_mfma_f32_16x16x32_f16(al, bh2, acc2, 0, 0, 0);
    acc2 = __builtin_amdgcn_mfma_f32_16x16x32_f16(ah, bl2, acc2, 0, 0, 0);
    acc2 = __builtin_amdgcn_mfma_f32_16x16x32_f16(ah, bh2, acc2, 0, 0, 0);
    acc3 = __builtin_amdgcn_mfma_f32_16x16x32_f16(al, bh3, acc3, 0, 0, 0);
    acc3 = __builtin_amdgcn_mfma_f32_16x16x32_f16(ah, bl3, acc3, 0, 0, 0);
    acc3 = __builtin_amdgcn_mfma_f32_16x16x32_f16(ah, bh3, acc3, 0, 0, 0);
  }

  const int K = topk_p[0];
  const bool doMask = (K > 0 && K < N_E);
  const float b2v0 = b2[c], b2v1 = b2[16 + c], b2v2 = b2[32 + c],
              b2v3 = b2[48 + c];

#pragma unroll
  for (int r = 0; r < 4; ++r) {
    const int row = rowbase + kg * 4 + r;
    float* lg = out_logits + (size_t)row * N_E;
    float* mk = out_masked + (size_t)row * N_E;
    float* pb = out_probs  + (size_t)row * N_E;

    const float v0 = acc0[r] + b2v0;
    const float v1 = acc1[r] + b2v1;
    const float v2 = acc2[r] + b2v2;
    const float v3 = acc3[r] + b2v3;
    lg[c] = v0; lg[16 + c] = v1; lg[32 + c] = v2; lg[48 + c] = v3;

    // ---- top-k (argmax K times over 16 lanes x 4 frags, min-idx ties) ----
    bool s0 = true, s1 = true, s2 = true, s3 = true;
    if (doMask) {
      s0 = s1 = s2 = s3 = false;
      float c0 = v0, c1 = v1, c2 = v2, c3 = v3;
      for (int it = 0; it < K; ++it) {
        float m = c0; int mi = c;
        if (c1 > m) { m = c1; mi = 16 + c; }
        if (c2 > m) { m = c2; mi = 32 + c; }
        if (c3 > m) { m = c3; mi = 48 + c; }
#pragma unroll
        for (int off = 1; off <= 8; off <<= 1) {
          const float om = __shfl_xor(m, off);
          const int   oi = __shfl_xor(mi, off);
          if (om > m || (om == m && oi < mi)) { m = om; mi = oi; }
        }
        if ((mi & 15) == c) {
          const int f = mi >> 4;
          s0 = s0 || (f == 0); c0 = (f == 0) ? -FLT_MAX : c0;
          s1 = s1 || (f == 1); c1 = (f == 1) ? -FLT_MAX : c1;
          s2 = s2 || (f == 2); c2 = (f == 2) ? -FLT_MAX : c2;
          s3 = s3 || (f == 3); c3 = (f == 3) ? -FLT_MAX : c3;
        }
      }
    }
    const float m0 = s0 ? v0 : NEG_INF_VAL;
    const float m1 = s1 ? v1 : NEG_INF_VAL;
    const float m2 = s2 ? v2 : NEG_INF_VAL;
    const float m3 = s3 ? v3 : NEG_INF_VAL;
    mk[c] = m0; mk[16 + c] = m1; mk[32 + c] = m2; mk[48 + c] = m3;

    // ---- softmax over masked ----
    float mx = fmaxf(fmaxf(m0, m1), fmaxf(m2, m3));
#pragma unroll
    for (int off = 1; off <= 8; off <<= 1) mx = fmaxf(mx, __shfl_xor(mx, off));
    const float e0 = __expf(m0 - mx);
    const float e1 = __expf(m1 - mx);
    const float e2 = __expf(m2 - mx);
    const float e3 = __expf(m3 - mx);
    float sm = e0 + e1 + e2 + e3;
#pragma unroll
    for (int off = 1; off <= 8; off <<= 1) sm += __shfl_xor(sm, off);
    const float inv = 1.0f / sm;
    pb[c] = e0 * inv; pb[16 + c] = e1 * inv; pb[32 + c] = e2 * inv;
    pb[48 + c] = e3 * inv;
  }
}

// ============================== launcher ===================================
extern "C" void kernel_launch(void* const* d_in, const int* in_sizes, int n_in,
                              void* d_out, int out_size, void* d_ws,
                              size_t ws_size, hipStream_t stream) {
  const float* x  = (const float*)d_in[0];
  const float* w1 = (const float*)d_in[1];
  const float* b1 = (const float*)d_in[2];
  const float* w2 = (const float*)d_in[3];
  const float* b2 = (const float*)d_in[4];
  const int* topk = (const int*)d_in[5];

  char* ws = (char*)d_ws;
  _Float16* w1pk_h = (_Float16*)(ws);                // 512 KB
  _Float16* w1pk_l = (_Float16*)(ws + 524288);       // 512 KB
  _Float16* w2hT   = (_Float16*)(ws + 1048576);      // 32 KB
  _Float16* w2lT   = (_Float16*)(ws + 1081344);      // 32 KB
  float*    hbuf   = (float*)(ws + 1114112);         // 33.5 MB

  float* out_logits = (float*)d_out;
  float* out_masked = out_logits + (size_t)N_ROWS * N_E;
  float* out_probs  = out_masked + (size_t)N_ROWS * N_E;

  split_weights_kernel<<<(D_IN * D_H + D_H * N_E) / 256, 256, 0, stream>>>(
      w1, w2, w1pk_h, w1pk_l, w2hT, w2lT);

  gemm1_mfma_kernel<<<N_ROWS / 64, 256, 0, stream>>>(x, w1pk_h, w1pk_l, b1,
                                                     hbuf);

  router_mfma_kernel<<<N_ROWS / 64, 256, 0, stream>>>(
      hbuf, w2hT, w2lT, b2, topk, out_logits, out_masked, out_probs);
}

// Round 6
// 81.895 us; speedup vs baseline: 1.6042x; 1.2499x over previous
//
#include <hip/hip_runtime.h>
#include <hip/hip_bf16.h>
#include <float.h>

// ---------------------------------------------------------------------------
// StageJointExpertRouter fused: h = relu(x@w1+b1) -> logits = h@w2+b2 ->
// top-k mask -> softmax, all in one kernel per 64-row tile.
// Split-fp16 MFMA (al*bh + ah*bl + ah*bh, f32 accum) for both GEMMs:
// logit deviation ~1e-6 (f32-rounding class) -> top-k safe (passed 4x).
// ---------------------------------------------------------------------------

#define N_ROWS 32768
#define D_IN   1024
#define D_H    256
#define N_E    64
#define NEG_INF_VAL (-1000000000.0f)

typedef _Float16 f16x8 __attribute__((ext_vector_type(8)));
typedef float    f32x4  __attribute__((ext_vector_type(4)));
typedef float    f32x16 __attribute__((ext_vector_type(16)));

#define MM32(A, B, C) __builtin_amdgcn_mfma_f32_32x32x16_f16(A, B, C, 0, 0, 0)
#define MM16(A, B, C) __builtin_amdgcn_mfma_f32_16x16x32_f16(A, B, C, 0, 0, 0)

// ========= Kernel 0: split + fragment-pack weights =========================
// w1 -> w1pk_h/l: chunk(wv,it,kf,nf,lane), col n = wv*64+nf*32+(lane&31),
//       k = it*64+kf*16+(lane>>5)*8+j   (for 32x32x16 B-frags)
// w2 -> w2pk_h/l: chunk(s,f,lane), e = f*16+(lane&15),
//       k = s*32+(lane>>4)*8+j          (for 16x16x32 B-frags)
__global__ __launch_bounds__(256) void split_weights_kernel(
    const float* __restrict__ w1, const float* __restrict__ w2,
    _Float16* __restrict__ w1pk_h, _Float16* __restrict__ w1pk_l,
    _Float16* __restrict__ w2pk_h, _Float16* __restrict__ w2pk_l) {
  int idx = blockIdx.x * 256 + threadIdx.x;
  if (idx < D_IN * D_H) {
    const int k = idx >> 8;   // 0..1023
    const int n = idx & 255;
    const float v = w1[idx];
    const _Float16 hi = (_Float16)v;
    const _Float16 lo = (_Float16)(v - (float)hi);
    const int wv = n >> 6, nf = (n >> 5) & 1, l31 = n & 31;
    const int it = k >> 6, kf = (k >> 4) & 3, kg = (k >> 3) & 1, j = k & 7;
    const int lane = kg * 32 + l31;
    const int off = ((((wv * 16 + it) * 4 + kf) * 2 + nf) * 64 + lane) * 8 + j;
    w1pk_h[off] = hi;
    w1pk_l[off] = lo;
  } else {
    idx -= D_IN * D_H;        // 0..16383
    const int k = idx >> 6;   // 0..255
    const int e = idx & 63;
    const float v = w2[idx];
    const _Float16 hi = (_Float16)v;
    const _Float16 lo = (_Float16)(v - (float)hi);
    const int s = k >> 5, kg = (k >> 3) & 3, j = k & 7;
    const int f = e >> 4, cc = e & 15;
    const int lane = kg * 16 + cc;
    const int off = ((s * 4 + f) * 64 + lane) * 8 + j;
    w2pk_h[off] = hi;
    w2pk_l[off] = lo;
  }
}

// ================= Fused kernel: GEMM1 + GEMM2 + topk + softmax ============
// 512 blocks x 256 thr (4 waves); tile 64 rows x 256 cols.
// GEMM1: wave wv owns cols [wv*64, wv*64+64) as 2x2 frags of 32x32.
//   A (x): split hi/lo fp16, LDS dbuf (BK=64, 256B rows, XOR swz), x-prefetch
//   depth 2 (sa/sb slots).  B (w1): frag-packed, global->reg, dbuf (uh/vh).
// Then h -> LDS (fp16 hi/lo planes, 32KB each, swz (col*2)^((row&7)<<4)).
// GEMM2: wave wv does rows [wv*16, wv*16+16) x 64 experts, w2 frag-packed
// global->reg, 96 MFMA 16x16x32; then top-k + softmax per row (router logic).
__global__ __launch_bounds__(256, 2) void fused_router_kernel(
    const float* __restrict__ x, const _Float16* __restrict__ w1pk_h,
    const _Float16* __restrict__ w1pk_l, const float* __restrict__ b1,
    const _Float16* __restrict__ w2pk_h, const _Float16* __restrict__ w2pk_l,
    const float* __restrict__ b2, const int* __restrict__ topk_p,
    float* __restrict__ out_logits, float* __restrict__ out_masked,
    float* __restrict__ out_probs) {
  __shared__ char lds[65536];
  // [0,32K): GEMM1 A-staging dbuf (2x16K)  -> later h hi-plane (64 rows x 512B)
  // [32K,64K): h lo-plane

  const int t  = threadIdx.x;
  const int m0 = blockIdx.x * 64;

  // staging coords
  const int srow = t >> 2;            // 0..63
  const int skb2 = (t & 3) * 32;      // byte offset of 16-elem slice
  const int sw   = (srow & 7) << 4;

  // fragment coords
  const int wv   = t >> 6;            // wave 0..3
  const int lane = t & 63;
  const int l31  = lane & 31;
  const int kg   = lane >> 5;

  const float* xrowp = x + (size_t)(m0 + srow) * D_IN + (t & 3) * 16;
  const f16x8* bph = (const f16x8*)w1pk_h;
  const f16x8* bpl = (const f16x8*)w1pk_l;

  f32x16 acc00, acc01, acc10, acc11;
#pragma unroll
  for (int i = 0; i < 16; ++i) {
    acc00[i] = 0.f; acc01[i] = 0.f; acc10[i] = 0.f; acc11[i] = 0.f;
  }

  f16x8 uh00, uh01, uh10, uh11, uh20, uh21, uh30, uh31;
  f16x8 ul00, ul01, ul10, ul11, ul20, ul21, ul30, ul31;
  f16x8 vh00, vh01, vh10, vh11, vh20, vh21, vh30, vh31;
  f16x8 vl00, vl01, vl10, vl11, vl20, vl21, vl30, vl31;
  float4 sa0, sa1, sa2, sa3, sb0, sb1, sb2, sb3;

#define STAGE_WRITE(bufi, q0, q1, q2, q3)                                    \
  do {                                                                       \
    const float vv[16] = {q0.x, q0.y, q0.z, q0.w, q1.x, q1.y, q1.z, q1.w,    \
                          q2.x, q2.y, q2.z, q2.w, q3.x, q3.y, q3.z, q3.w};   \
    f16x8 hi0, hi1, lo0, lo1;                                                \
    _Pragma("unroll") for (int j = 0; j < 8; ++j) {                          \
      const _Float16 hv = (_Float16)vv[j];                                   \
      hi0[j] = hv; lo0[j] = (_Float16)(vv[j] - (float)hv);                   \
    }                                                                        \
    _Pragma("unroll") for (int j = 0; j < 8; ++j) {                          \
      const _Float16 hv = (_Float16)vv[8 + j];                               \
      hi1[j] = hv; lo1[j] = (_Float16)(vv[8 + j] - (float)hv);               \
    }                                                                        \
    char* bb = lds + (bufi) * 16384 + srow * 256;                            \
    *(f16x8*)(bb + ((skb2 + 0) ^ sw)) = hi0;                                 \
    *(f16x8*)(bb + ((skb2 + 16) ^ sw)) = hi1;                                \
    *(f16x8*)(bb + 128 + ((skb2 + 0) ^ sw)) = lo0;                           \
    *(f16x8*)(bb + 128 + ((skb2 + 16) ^ sw)) = lo1;                          \
  } while (0)

#define LOAD_B(BH, BL, itv)                                                  \
  do {                                                                       \
    const int ch = (wv * 16 + (itv)) * 512 + lane;                           \
    BH##00 = bph[ch + 0 * 64]; BH##01 = bph[ch + 1 * 64];                    \
    BH##10 = bph[ch + 2 * 64]; BH##11 = bph[ch + 3 * 64];                    \
    BH##20 = bph[ch + 4 * 64]; BH##21 = bph[ch + 5 * 64];                    \
    BH##30 = bph[ch + 6 * 64]; BH##31 = bph[ch + 7 * 64];                    \
    BL##00 = bpl[ch + 0 * 64]; BL##01 = bpl[ch + 1 * 64];                    \
    BL##10 = bpl[ch + 2 * 64]; BL##11 = bpl[ch + 3 * 64];                    \
    BL##20 = bpl[ch + 4 * 64]; BL##21 = bpl[ch + 5 * 64];                    \
    BL##30 = bpl[ch + 6 * 64]; BL##31 = bpl[ch + 7 * 64];                    \
  } while (0)

  // 4-way interleave across the 4 acc chains; per-acc term order preserved
  // (al*bh, ah*bl, ah*bh) for numerics identical to prior rounds.
#define MFMA_KF(rb, kfv, BH0, BL0, BH1, BL1)                                 \
  do {                                                                       \
    const int kb = (kfv) * 32 + kg * 16;                                     \
    const char* ap0 = (rb) + l31 * 256 + (kb ^ ((l31 & 7) << 4));            \
    const char* ap1 = ap0 + 32 * 256;                                        \
    const f16x8 ah0 = *(const f16x8*)(ap0);                                  \
    const f16x8 al0 = *(const f16x8*)(ap0 + 128);                            \
    const f16x8 ah1 = *(const f16x8*)(ap1);                                  \
    const f16x8 al1 = *(const f16x8*)(ap1 + 128);                            \
    acc00 = MM32(al0, BH0, acc00); acc01 = MM32(al0, BH1, acc01);            \
    acc10 = MM32(al1, BH0, acc10); acc11 = MM32(al1, BH1, acc11);            \
    acc00 = MM32(ah0, BL0, acc00); acc01 = MM32(ah0, BL1, acc01);            \
    acc10 = MM32(ah1, BL0, acc10); acc11 = MM32(ah1, BL1, acc11);            \
    acc00 = MM32(ah0, BH0, acc00); acc01 = MM32(ah0, BH1, acc01);            \
    acc10 = MM32(ah1, BH0, acc10); acc11 = MM32(ah1, BH1, acc11);            \
  } while (0)

  // x-prefetch depth 2: at iter it, issue x(it+2) into SL; stage SS=x(it+1).
#define GSTEP(ITV, LB, CH, CL, NH, NL, SL, SS)                               \
  do {                                                                       \
    if ((ITV) + 2 < 16) {                                                    \
      const float4* xp = (const float4*)(xrowp + ((ITV) + 2) * 64);          \
      SL##0 = xp[0]; SL##1 = xp[1]; SL##2 = xp[2]; SL##3 = xp[3];            \
    }                                                                        \
    if ((ITV) + 1 < 16) LOAD_B(NH, NL, (ITV) + 1);                           \
    const char* rb = lds + (LB) * 16384;                                     \
    MFMA_KF(rb, 0, CH##00, CL##00, CH##01, CL##01);                          \
    MFMA_KF(rb, 1, CH##10, CL##10, CH##11, CL##11);                          \
    MFMA_KF(rb, 2, CH##20, CL##20, CH##21, CL##21);                          \
    MFMA_KF(rb, 3, CH##30, CL##30, CH##31, CL##31);                          \
    if ((ITV) + 1 < 16) STAGE_WRITE(1 - (LB), SS##0, SS##1, SS##2, SS##3);   \
    __syncthreads();                                                         \
  } while (0)

  // ---- prologue: stage x(0), prefetch x(1)->sb, load B(0) ----
  {
    const float4* xp = (const float4*)(xrowp);
    const float4 q0 = xp[0], q1 = xp[1], q2 = xp[2], q3 = xp[3];
    STAGE_WRITE(0, q0, q1, q2, q3);
    const float4* xp1 = (const float4*)(xrowp + 64);
    sb0 = xp1[0]; sb1 = xp1[1]; sb2 = xp1[2]; sb3 = xp1[3];
    LOAD_B(uh, ul, 0);
  }
  __syncthreads();

#pragma unroll
  for (int ii = 0; ii < 8; ++ii) {
    GSTEP(2 * ii,     0, uh, ul, vh, vl, sa, sb);
    GSTEP(2 * ii + 1, 1, vh, vl, uh, ul, sb, sa);
  }
  // last GSTEP's __syncthreads(): all waves done reading staging bufs.

  // ---- h -> LDS (fp16 hi/lo planes), swz byte = row*512 + (col*2 ^ swz) ----
#define EPI(ACC, MF, NF)                                                     \
  do {                                                                       \
    const int colg = wv * 64 + (NF) * 32 + l31;                              \
    const float bias = b1[colg];                                             \
    _Pragma("unroll") for (int r = 0; r < 16; ++r) {                         \
      const int row = (MF) * 32 + (r & 3) + 8 * (r >> 2) + 4 * kg;           \
      const float hv = fmaxf(ACC[r] + bias, 0.0f);                           \
      const _Float16 hhi = (_Float16)hv;                                     \
      const _Float16 hlo = (_Float16)(hv - (float)hhi);                      \
      const int byo = row * 512 + ((colg * 2) ^ ((row & 7) << 4));           \
      *(_Float16*)(lds + byo) = hhi;                                         \
      *(_Float16*)(lds + 32768 + byo) = hlo;                                 \
    }                                                                        \
  } while (0)

  EPI(acc00, 0, 0); EPI(acc01, 0, 1); EPI(acc10, 1, 0); EPI(acc11, 1, 1);
#undef EPI
  __syncthreads();

  // ================= GEMM2 + top-k + softmax (per wave: 16 rows) ===========
  const int c   = lane & 15;   // A-row / B-col selector
  const int kg4 = lane >> 4;   // k-group 0..3 (also C row-group)
  const int rowl = wv * 16 + c;
  const int sw2 = (rowl & 7) << 4;
  const char* hhb = lds + rowl * 512;
  const char* hlb = lds + 32768 + rowl * 512;
  const f16x8* b2ph = (const f16x8*)w2pk_h;
  const f16x8* b2pl = (const f16x8*)w2pk_l;

  f32x4 r0 = {0.f, 0.f, 0.f, 0.f};
  f32x4 r1 = {0.f, 0.f, 0.f, 0.f};
  f32x4 r2 = {0.f, 0.f, 0.f, 0.f};
  f32x4 r3 = {0.f, 0.f, 0.f, 0.f};

#pragma unroll
  for (int s = 0; s < 8; ++s) {
    const int kb = (s * 64 + kg4 * 16) ^ sw2;
    const f16x8 ah = *(const f16x8*)(hhb + kb);
    const f16x8 al = *(const f16x8*)(hlb + kb);
    const int ch = s * 256 + lane;     // ((s*4+f)*64+lane), f stride 64
    const f16x8 bh0 = b2ph[ch +   0], bh1 = b2ph[ch +  64];
    const f16x8 bh2 = b2ph[ch + 128], bh3 = b2ph[ch + 192];
    const f16x8 bl0 = b2pl[ch +   0], bl1 = b2pl[ch +  64];
    const f16x8 bl2 = b2pl[ch + 128], bl3 = b2pl[ch + 192];
    r0 = MM16(al, bh0, r0); r1 = MM16(al, bh1, r1);
    r2 = MM16(al, bh2, r2); r3 = MM16(al, bh3, r3);
    r0 = MM16(ah, bl0, r0); r1 = MM16(ah, bl1, r1);
    r2 = MM16(ah, bl2, r2); r3 = MM16(ah, bl3, r3);
    r0 = MM16(ah, bh0, r0); r1 = MM16(ah, bh1, r1);
    r2 = MM16(ah, bh2, r2); r3 = MM16(ah, bh3, r3);
  }

  const int K = topk_p[0];
  const bool doMask = (K > 0 && K < N_E);
  const float b2v0 = b2[c], b2v1 = b2[16 + c], b2v2 = b2[32 + c],
              b2v3 = b2[48 + c];
  const int rowbase = m0 + wv * 16;

#pragma unroll
  for (int r = 0; r < 4; ++r) {
    const int row = rowbase + kg4 * 4 + r;
    float* lg = out_logits + (size_t)row * N_E;
    float* mk = out_masked + (size_t)row * N_E;
    float* pb = out_probs  + (size_t)row * N_E;

    const float v0 = r0[r] + b2v0;
    const float v1 = r1[r] + b2v1;
    const float v2 = r2[r] + b2v2;
    const float v3 = r3[r] + b2v3;
    lg[c] = v0; lg[16 + c] = v1; lg[32 + c] = v2; lg[48 + c] = v3;

    // ---- top-k (argmax K times over 16 lanes x 4 frags, min-idx ties) ----
    bool s0 = true, s1 = true, s2 = true, s3 = true;
    if (doMask) {
      s0 = s1 = s2 = s3 = false;
      float c0 = v0, c1 = v1, c2 = v2, c3 = v3;
      for (int it = 0; it < K; ++it) {
        float m = c0; int mi = c;
        if (c1 > m) { m = c1; mi = 16 + c; }
        if (c2 > m) { m = c2; mi = 32 + c; }
        if (c3 > m) { m = c3; mi = 48 + c; }
#pragma unroll
        for (int off = 1; off <= 8; off <<= 1) {
          const float om = __shfl_xor(m, off);
          const int   oi = __shfl_xor(mi, off);
          if (om > m || (om == m && oi < mi)) { m = om; mi = oi; }
        }
        if ((mi & 15) == c) {
          const int f = mi >> 4;
          s0 = s0 || (f == 0); c0 = (f == 0) ? -FLT_MAX : c0;
          s1 = s1 || (f == 1); c1 = (f == 1) ? -FLT_MAX : c1;
          s2 = s2 || (f == 2); c2 = (f == 2) ? -FLT_MAX : c2;
          s3 = s3 || (f == 3); c3 = (f == 3) ? -FLT_MAX : c3;
        }
      }
    }
    const float m0v = s0 ? v0 : NEG_INF_VAL;
    const float m1v = s1 ? v1 : NEG_INF_VAL;
    const float m2v = s2 ? v2 : NEG_INF_VAL;
    const float m3v = s3 ? v3 : NEG_INF_VAL;
    mk[c] = m0v; mk[16 + c] = m1v; mk[32 + c] = m2v; mk[48 + c] = m3v;

    // ---- softmax over masked (exp(-1e9-mx) underflows to 0 as in ref) ----
    float mx = fmaxf(fmaxf(m0v, m1v), fmaxf(m2v, m3v));
#pragma unroll
    for (int off = 1; off <= 8; off <<= 1) mx = fmaxf(mx, __shfl_xor(mx, off));
    const float e0 = __expf(m0v - mx);
    const float e1 = __expf(m1v - mx);
    const float e2 = __expf(m2v - mx);
    const float e3 = __expf(m3v - mx);
    float sm = e0 + e1 + e2 + e3;
#pragma unroll
    for (int off = 1; off <= 8; off <<= 1) sm += __shfl_xor(sm, off);
    const float inv = 1.0f / sm;
    pb[c] = e0 * inv; pb[16 + c] = e1 * inv; pb[32 + c] = e2 * inv;
    pb[48 + c] = e3 * inv;
  }
#undef GSTEP
#undef MFMA_KF
#undef LOAD_B
#undef STAGE_WRITE
}

// ============================== launcher ===================================
extern "C" void kernel_launch(void* const* d_in, const int* in_sizes, int n_in,
                              void* d_out, int out_size, void* d_ws,
                              size_t ws_size, hipStream_t stream) {
  const float* x  = (const float*)d_in[0];
  const float* w1 = (const float*)d_in[1];
  const float* b1 = (const float*)d_in[2];
  const float* w2 = (const float*)d_in[3];
  const float* b2 = (const float*)d_in[4];
  const int* topk = (const int*)d_in[5];

  char* ws = (char*)d_ws;
  _Float16* w1pk_h = (_Float16*)(ws);                // 512 KB
  _Float16* w1pk_l = (_Float16*)(ws + 524288);       // 512 KB
  _Float16* w2pk_h = (_Float16*)(ws + 1048576);      // 32 KB
  _Float16* w2pk_l = (_Float16*)(ws + 1081344);      // 32 KB

  float* out_logits = (float*)d_out;
  float* out_masked = out_logits + (size_t)N_ROWS * N_E;
  float* out_probs  = out_masked + (size_t)N_ROWS * N_E;

  split_weights_kernel<<<(D_IN * D_H + D_H * N_E) / 256, 256, 0, stream>>>(
      w1, w2, w1pk_h, w1pk_l, w2pk_h, w2pk_l);

  fused_router_kernel<<<N_ROWS / 64, 256, 0, stream>>>(
      x, w1pk_h, w1pk_l, b1, w2pk_h, w2pk_l, b2, topk, out_logits, out_masked,
      out_probs);
}